// Round 3
// baseline (604.521 us; speedup 1.0000x reference)
//
#include <hip/hip_runtime.h>
#include <math.h>
#include <stdint.h>

#define DIM_ 1024
#define HEADS_ 16
#define DK_ 64
#define B_ 2
#define L_ 2048
#define BH_ (B_*HEADS_)
#define M_ (B_*L_)

typedef __attribute__((ext_vector_type(4))) float f32x4;
typedef __attribute__((ext_vector_type(8))) short bf16x8;
typedef __attribute__((ext_vector_type(4))) short bf16x4;

#define QSCALE 0.18033688f   // 0.125 * log2(e): softmax done in exp2 domain

static __device__ __forceinline__ short f2bf(float f) {
    uint32_t u = __builtin_bit_cast(uint32_t, f);
    u += 0x7fffu + ((u >> 16) & 1u);          // round-to-nearest-even
    return (short)(u >> 16);
}

// async global->LDS, 16B per lane; lds dest = wave-uniform base + lane*16
static __device__ __forceinline__ void gload16(const void* g, void* l) {
    __builtin_amdgcn_global_load_lds(
        (const __attribute__((address_space(1))) unsigned int*)g,
        (__attribute__((address_space(3))) unsigned int*)l, 16, 0, 0);
}

// ------------------------------------------------------------ prep: fp32 -> bf16
__global__ __launch_bounds__(256)
void cvt_bf16(const float* __restrict__ a, const float* __restrict__ b,
              short* __restrict__ ao, short* __restrict__ bo)
{
    const int id = blockIdx.x * 256 + threadIdx.x;
    const int nA = (M_ * DIM_) / 8;
    const float* src = (id < nA) ? a : b;
    short* dst = (id < nA) ? ao : bo;
    const int c = (id < nA) ? id : id - nA;
    const f32x4 v0 = *(const f32x4*)&src[(size_t)c * 8];
    const f32x4 v1 = *(const f32x4*)&src[(size_t)c * 8 + 4];
    bf16x8 o;
#pragma unroll
    for (int i = 0; i < 4; ++i) { o[i] = f2bf(v0[i]); o[4 + i] = f2bf(v1[i]); }
    *(bf16x8*)&dst[(size_t)c * 8] = o;
}

// ------------------------------------------------------------ prep: W[k][n] -> WT[n][k] bf16
__global__ __launch_bounds__(256)
void wtrans(const float* __restrict__ Wq, const float* __restrict__ Wk,
            const float* __restrict__ Wv, const float* __restrict__ Wo,
            short* __restrict__ WqT, short* __restrict__ WkT,
            short* __restrict__ WvT, short* __restrict__ WoT)
{
    const int z = blockIdx.z;
    const int K = (z == 3) ? 2 * DIM_ : DIM_;
    const int k0 = blockIdx.x * 64;
    if (k0 >= K) return;
    const int n0 = blockIdx.y * 64;
    const float* W = (z == 0) ? Wq : (z == 1) ? Wk : (z == 2) ? Wv : Wo;
    short* WT = (z == 0) ? WqT : (z == 1) ? WkT : (z == 2) ? WvT : WoT;

    __shared__ float ts[64][65];
    const int tid = threadIdx.x;
    {
        const int k = tid >> 2, noff = (tid & 3) * 16;
#pragma unroll
        for (int i = 0; i < 4; ++i)
            *(f32x4*)&ts[k][noff + i * 4] =
                *(const f32x4*)&W[(size_t)(k0 + k) * DIM_ + n0 + noff + i * 4];
    }
    __syncthreads();
    {
        const int n = tid >> 2, koff = (tid & 3) * 16;
#pragma unroll
        for (int c = 0; c < 2; ++c) {
            bf16x8 o;
#pragma unroll
            for (int i = 0; i < 8; ++i) o[i] = f2bf(ts[koff + c * 8 + i][n]);
            *(bf16x8*)&WT[(size_t)(n0 + n) * K + k0 + koff + c * 8] = o;
        }
    }
}

// ------------------------------------------------------------ QKV GEMM (MFMA, gload_lds, BK=64, XOR-swizzled LDS)
__global__ __launch_bounds__(256)
void qkv_mfma(const short* __restrict__ xoutb, const short* __restrict__ xctxb,
              const short* __restrict__ WqT, const short* __restrict__ WkT,
              const short* __restrict__ WvT,
              const float* __restrict__ bq, const float* __restrict__ bk,
              const float* __restrict__ bv,
              short* __restrict__ qh, short* __restrict__ kh, short* __restrict__ vT)
{
    const int z = blockIdx.z;
    const short* A  = (z == 0) ? xoutb : xctxb;
    const short* Bt = (z == 0) ? WqT : (z == 1) ? WkT : WvT;
    const float* bias = (z == 0) ? bq : (z == 1) ? bk : bv;

    const int col0 = blockIdx.x * 128;
    const int row0 = blockIdx.y * 128;
    const int tid = threadIdx.x;
    const int lane = tid & 63;
    const int w = tid >> 6;
    const int wm = (w >> 1) * 64, wn = (w & 1) * 64;
    const int l15 = lane & 15, g = lane >> 4;
    const int sub = lane >> 3, slt = lane & 7;

    __shared__ short As[128 * 64];
    __shared__ short Bs[128 * 64];

    // per-lane staging source pointers (swizzle folded into global col slot)
    const short* pA[4]; const short* pB[4]; short* ldsA[4]; short* ldsB[4];
#pragma unroll
    for (int i = 0; i < 4; ++i) {
        const int r = w * 32 + i * 8 + sub;          // LDS row this lane feeds
        const int sc = ((slt ^ (r & 7)) * 8);        // swizzled 8-short slot
        pA[i] = A  + (size_t)(row0 + r) * DIM_ + sc;
        pB[i] = Bt + (size_t)(col0 + r) * DIM_ + sc;
        ldsA[i] = &As[(w * 32 + i * 8) * 64];
        ldsB[i] = &Bs[(w * 32 + i * 8) * 64];
    }

    f32x4 acc[4][4];
#pragma unroll
    for (int mi = 0; mi < 4; ++mi)
#pragma unroll
        for (int ni = 0; ni < 4; ++ni) acc[mi][ni] = (f32x4)0.f;

    for (int k0 = 0; k0 < DIM_; k0 += 64) {
#pragma unroll
        for (int i = 0; i < 4; ++i) {
            gload16(pA[i] + k0, ldsA[i]);
            gload16(pB[i] + k0, ldsB[i]);
        }
        __syncthreads();
        bf16x8 af[4][2], bfr[4][2];
#pragma unroll
        for (int mi = 0; mi < 4; ++mi) {
            const int wa = wm + mi * 16 + l15;
#pragma unroll
            for (int ks = 0; ks < 2; ++ks)
                af[mi][ks] = *(const bf16x8*)&As[wa * 64 + (((ks * 4 + g) ^ (wa & 7)) * 8)];
        }
#pragma unroll
        for (int ni = 0; ni < 4; ++ni) {
            const int wb = wn + ni * 16 + l15;
#pragma unroll
            for (int ks = 0; ks < 2; ++ks)
                bfr[ni][ks] = *(const bf16x8*)&Bs[wb * 64 + (((ks * 4 + g) ^ (wb & 7)) * 8)];
        }
#pragma unroll
        for (int mi = 0; mi < 4; ++mi)
#pragma unroll
            for (int ni = 0; ni < 4; ++ni)
#pragma unroll
                for (int ks = 0; ks < 2; ++ks)
                    acc[mi][ni] = __builtin_amdgcn_mfma_f32_16x16x32_bf16(af[mi][ks], bfr[ni][ks], acc[mi][ni], 0, 0, 0);
        __syncthreads();
    }

#pragma unroll
    for (int ni = 0; ni < 4; ++ni) {
        const int col = col0 + wn + ni * 16 + l15;
        const int h = col >> 6, dk = col & 63;
        const float bb = bias[col];
#pragma unroll
        for (int mi = 0; mi < 4; ++mi) {
            const int rowb = row0 + wm + mi * 16 + g * 4;
            const int b = rowb >> 11;
            const int l = rowb & (L_ - 1);
            const int bh = b * 16 + h;
            if (z == 2) {
                bf16x4 o;
#pragma unroll
                for (int r = 0; r < 4; ++r) o[r] = f2bf(acc[mi][ni][r] + bb);
                *(bf16x4*)&vT[(size_t)(bh * 64 + dk) * L_ + l] = o;
            } else {
                short* dst = (z == 0) ? qh : kh;
                const float sc = (z == 0) ? QSCALE : 1.0f;
#pragma unroll
                for (int r = 0; r < 4; ++r)
                    dst[((size_t)bh * L_ + l + r) * DK_ + dk] = f2bf((acc[mi][ni][r] + bb) * sc);
            }
        }
    }
}

// ------------------------------------------------------------ fused attention
// pass 1: barrier-free per-lane online stats; pass 2: recompute + write attn + PV.
// K/V read directly from global (L2-resident per head); only Ps lives in LDS.
__global__ __launch_bounds__(256)
void attn_mfma(const short* __restrict__ qh, const short* __restrict__ kh,
               const short* __restrict__ vT,
               float* __restrict__ attn, short* __restrict__ ctxTb)
{
    const int bh = blockIdx.y;
    const int q0 = blockIdx.x * 64;
    const int tid = threadIdx.x;
    const int lane = tid & 63;
    const int w = tid >> 6;
    const int l15 = lane & 15, g = lane >> 4;
    const int lk = g * 8;

    __shared__ float Ps[64][68];

    bf16x8 qf[2];
#pragma unroll
    for (int ks = 0; ks < 2; ++ks)
        qf[ks] = *(const bf16x8*)&qh[((size_t)bh * L_ + q0 + w * 16 + l15) * DK_ + ks * 32 + lk];

    // per-lane fragment offsets (elements) into K rows / V^T rows
    const short* kbase = kh + (size_t)bh * L_ * DK_;
    const short* vbase = vT + (size_t)bh * DK_ * L_;
    size_t koff[4][2], voff[4][2];
#pragma unroll
    for (int c = 0; c < 4; ++c)
#pragma unroll
        for (int ks = 0; ks < 2; ++ks) {
            koff[c][ks] = (size_t)(c * 16 + l15) * DK_ + ks * 32 + lk;
            voff[c][ks] = (size_t)(c * 16 + l15) * L_ + ks * 32 + lk;
        }

    // ---- pass 1: per-lane online stats (no barriers, no LDS)
    float m[4], s[4];
#pragma unroll
    for (int r = 0; r < 4; ++r) { m[r] = -1e30f; s[r] = 0.f; }

    for (int j0 = 0; j0 < L_; j0 += 64) {
        const short* kt = kbase + (size_t)j0 * DK_;
        f32x4 sa[4];
#pragma unroll
        for (int c = 0; c < 4; ++c) sa[c] = (f32x4)0.f;
#pragma unroll
        for (int c = 0; c < 4; ++c)
#pragma unroll
            for (int ks = 0; ks < 2; ++ks) {
                const bf16x8 kb = *(const bf16x8*)&kt[koff[c][ks]];
                sa[c] = __builtin_amdgcn_mfma_f32_16x16x32_bf16(qf[ks], kb, sa[c], 0, 0, 0);
            }
#pragma unroll
        for (int r = 0; r < 4; ++r) {
            const float tm = fmaxf(fmaxf(sa[0][r], sa[1][r]), fmaxf(sa[2][r], sa[3][r]));
            const float mn = fmaxf(m[r], tm);
            s[r] = s[r] * exp2f(m[r] - mn)
                 + exp2f(sa[0][r] - mn) + exp2f(sa[1][r] - mn)
                 + exp2f(sa[2][r] - mn) + exp2f(sa[3][r] - mn);
            m[r] = mn;
        }
    }
    // cross-lane combine over the 16-lane col groups
#pragma unroll
    for (int mask = 1; mask <= 8; mask <<= 1) {
#pragma unroll
        for (int r = 0; r < 4; ++r) {
            const float mo = __shfl_xor(m[r], mask);
            const float so = __shfl_xor(s[r], mask);
            const float mn = fmaxf(m[r], mo);
            s[r] = s[r] * exp2f(m[r] - mn) + so * exp2f(mo - mn);
            m[r] = mn;
        }
    }
    float inv_s[4];
#pragma unroll
    for (int r = 0; r < 4; ++r) inv_s[r] = 1.0f / s[r];

    f32x4 cacc[4];
#pragma unroll
    for (int nf = 0; nf < 4; ++nf) cacc[nf] = (f32x4)0.f;

    // ---- pass 2: recompute S, write attn, accumulate PV
    for (int j0 = 0; j0 < L_; j0 += 64) {
        const short* kt = kbase + (size_t)j0 * DK_;
        const short* vt = vbase + j0;
        f32x4 sa[4];
#pragma unroll
        for (int c = 0; c < 4; ++c) sa[c] = (f32x4)0.f;
#pragma unroll
        for (int c = 0; c < 4; ++c)
#pragma unroll
            for (int ks = 0; ks < 2; ++ks) {
                const bf16x8 kb = *(const bf16x8*)&kt[koff[c][ks]];
                sa[c] = __builtin_amdgcn_mfma_f32_16x16x32_bf16(qf[ks], kb, sa[c], 0, 0, 0);
            }
#pragma unroll
        for (int c = 0; c < 4; ++c)
#pragma unroll
            for (int r = 0; r < 4; ++r)
                Ps[w * 16 + g * 4 + r][c * 16 + l15] = exp2f(sa[c][r] - m[r]) * inv_s[r];
        __syncthreads();
        // coalesced attn write: 4 threads cover one 256B row segment
        {
            const int row = tid >> 2, coff = (tid & 3) * 16;
            float* dst = &attn[((size_t)bh * L_ + q0 + row) * L_ + j0 + coff];
#pragma unroll
            for (int i = 0; i < 4; ++i)
                *(f32x4*)&dst[i * 4] = *(const f32x4*)&Ps[row][coff + i * 4];
        }
        // P -> bf16 A-fragments
        bf16x8 pa[2];
#pragma unroll
        for (int ks = 0; ks < 2; ++ks) {
            const f32x4 p0 = *(const f32x4*)&Ps[w * 16 + l15][ks * 32 + lk];
            const f32x4 p1 = *(const f32x4*)&Ps[w * 16 + l15][ks * 32 + lk + 4];
            bf16x8 t;
#pragma unroll
            for (int i = 0; i < 4; ++i) { t[i] = f2bf(p0[i]); t[4 + i] = f2bf(p1[i]); }
            pa[ks] = t;
        }
        // PV with direct V^T fragment loads
#pragma unroll
        for (int nf = 0; nf < 4; ++nf)
#pragma unroll
            for (int ks = 0; ks < 2; ++ks) {
                const bf16x8 vb = *(const bf16x8*)&vt[voff[nf][ks]];
                cacc[nf] = __builtin_amdgcn_mfma_f32_16x16x32_bf16(pa[ks], vb, cacc[nf], 0, 0, 0);
            }
        __syncthreads();
    }

    // ctx^T epilogue (bf16, [BH][DK][L])
#pragma unroll
    for (int nf = 0; nf < 4; ++nf) {
        const int dk = nf * 16 + l15;
        const int q = q0 + w * 16 + g * 4;
        bf16x4 o;
#pragma unroll
        for (int r = 0; r < 4; ++r) o[r] = f2bf(cacc[nf][r]);
        *(bf16x4*)&ctxTb[(size_t)(bh * 64 + dk) * L_ + q] = o;
    }
}

// ------------------------------------------------------------ output projection (MFMA, gload_lds, gathered A)
__global__ __launch_bounds__(256)
void out_mfma(const short* __restrict__ ctxTb, const short* __restrict__ xoutb,
              const short* __restrict__ WoT, const float* __restrict__ bo,
              float* __restrict__ out)
{
    const int col0 = blockIdx.x * 128;
    const int row0 = blockIdx.y * 128;
    const int tid = threadIdx.x;
    const int lane = tid & 63;
    const int w = tid >> 6;
    const int wm = (w >> 1) * 64, wn = (w & 1) * 64;
    const int l15 = lane & 15, g = lane >> 4;
    const int sub = lane >> 3, slt = lane & 7;

    __shared__ short As[128 * 64];
    __shared__ short Bs[128 * 64];

    const short* pA1[4]; const short* pA2[4]; const short* pB[4];
    short* ldsA[4]; short* ldsB[4];
#pragma unroll
    for (int i = 0; i < 4; ++i) {
        const int r = w * 32 + i * 8 + sub;
        const int rr = row0 + r;
        const int b = rr >> 11, l_ = rr & (L_ - 1);
        const int bh = b * 16 + (l_ >> 7), d = (l_ & 127) >> 1;
        const size_t off1 = ((size_t)(bh * 64 + d) << 11) + (size_t)((l_ & 1) << 10);
        const int sc = ((slt ^ (r & 7)) * 8);
        pA1[i] = ctxTb + off1 + sc;                  // k in [0,1024)
        pA2[i] = xoutb + (size_t)rr * DIM_ + sc;     // k-1024 in [0,1024)
        pB[i]  = WoT + (size_t)(col0 + r) * (2 * DIM_) + sc;
        ldsA[i] = &As[(w * 32 + i * 8) * 64];
        ldsB[i] = &Bs[(w * 32 + i * 8) * 64];
    }

    f32x4 acc[4][4];
#pragma unroll
    for (int mi = 0; mi < 4; ++mi)
#pragma unroll
        for (int ni = 0; ni < 4; ++ni) acc[mi][ni] = (f32x4)0.f;

    for (int k0 = 0; k0 < 2 * DIM_; k0 += 64) {
        const bool first = (k0 < DIM_);
        const int kk = first ? k0 : k0 - DIM_;
#pragma unroll
        for (int i = 0; i < 4; ++i) {
            gload16(first ? (pA1[i] + kk) : (pA2[i] + kk), ldsA[i]);
            gload16(pB[i] + k0, ldsB[i]);
        }
        __syncthreads();
        bf16x8 af[4][2], bfr[4][2];
#pragma unroll
        for (int mi = 0; mi < 4; ++mi) {
            const int wa = wm + mi * 16 + l15;
#pragma unroll
            for (int ks = 0; ks < 2; ++ks)
                af[mi][ks] = *(const bf16x8*)&As[wa * 64 + (((ks * 4 + g) ^ (wa & 7)) * 8)];
        }
#pragma unroll
        for (int ni = 0; ni < 4; ++ni) {
            const int wb = wn + ni * 16 + l15;
#pragma unroll
            for (int ks = 0; ks < 2; ++ks)
                bfr[ni][ks] = *(const bf16x8*)&Bs[wb * 64 + (((ks * 4 + g) ^ (wb & 7)) * 8)];
        }
#pragma unroll
        for (int mi = 0; mi < 4; ++mi)
#pragma unroll
            for (int ni = 0; ni < 4; ++ni)
#pragma unroll
                for (int ks = 0; ks < 2; ++ks)
                    acc[mi][ni] = __builtin_amdgcn_mfma_f32_16x16x32_bf16(af[mi][ks], bfr[ni][ks], acc[mi][ni], 0, 0, 0);
        __syncthreads();
    }

#pragma unroll
    for (int ni = 0; ni < 4; ++ni) {
        const int col = col0 + wn + ni * 16 + l15;
        const float bb = bo[col];
#pragma unroll
        for (int mi = 0; mi < 4; ++mi) {
            const int rowb = row0 + wm + mi * 16 + g * 4;
#pragma unroll
            for (int r = 0; r < 4; ++r)
                out[(size_t)(rowb + r) * DIM_ + col] = tanhf(acc[mi][ni][r] + bb);
        }
    }
}

// ------------------------------------------------------------ launch
extern "C" void kernel_launch(void* const* d_in, const int* in_sizes, int n_in,
                              void* d_out, int out_size, void* d_ws, size_t ws_size,
                              hipStream_t stream)
{
    const float* xout = (const float*)d_in[0];
    const float* xctx = (const float*)d_in[1];
    const float* Wq = (const float*)d_in[2];
    const float* bq = (const float*)d_in[3];
    const float* Wk = (const float*)d_in[4];
    const float* bk = (const float*)d_in[5];
    const float* Wv = (const float*)d_in[6];
    const float* bv = (const float*)d_in[7];
    const float* Wo = (const float*)d_in[8];
    const float* bo = (const float*)d_in[9];

    float* out  = (float*)d_out;
    float* attn = out + (size_t)M_ * DIM_;

    short* ws = (short*)d_ws;
    short* xoutb = ws;
    short* xctxb = xoutb + (size_t)M_ * DIM_;
    short* WqT   = xctxb + (size_t)M_ * DIM_;
    short* WkT   = WqT + (size_t)DIM_ * DIM_;
    short* WvT   = WkT + (size_t)DIM_ * DIM_;
    short* WoT   = WvT + (size_t)DIM_ * DIM_;
    short* qh    = WoT + (size_t)2 * DIM_ * DIM_;
    short* kh    = qh + (size_t)BH_ * L_ * DK_;
    short* vT    = kh + (size_t)BH_ * L_ * DK_;
    short* ctxTb = vT + (size_t)BH_ * L_ * DK_;

    cvt_bf16<<<(2 * M_ * DIM_ / 8) / 256, 256, 0, stream>>>(xout, xctx, xoutb, xctxb);
    wtrans<<<dim3(32, 16, 4), 256, 0, stream>>>(Wq, Wk, Wv, Wo, WqT, WkT, WvT, WoT);
    qkv_mfma<<<dim3(DIM_ / 128, M_ / 128, 3), 256, 0, stream>>>(
        xoutb, xctxb, WqT, WkT, WvT, bq, bk, bv, qh, kh, vT);
    attn_mfma<<<dim3(L_ / 64, BH_), 256, 0, stream>>>(qh, kh, vT, attn, ctxTb);
    out_mfma<<<dim3(DIM_ / 128, M_ / 128), 256, 0, stream>>>(ctxTb, xoutb, WoT, bo, out);
}

// Round 4
// 356.103 us; speedup vs baseline: 1.6976x; 1.6976x over previous
//
#include <hip/hip_runtime.h>
#include <math.h>
#include <stdint.h>

#define DIM_ 1024
#define HEADS_ 16
#define DK_ 64
#define B_ 2
#define L_ 2048
#define BH_ (B_*HEADS_)
#define M_ (B_*L_)

typedef __attribute__((ext_vector_type(4))) float f32x4;
typedef __attribute__((ext_vector_type(8))) short bf16x8;
typedef __attribute__((ext_vector_type(4))) short bf16x4;

#define QSCALE 0.18033688f   // 0.125 * log2(e): softmax in exp2 domain

static __device__ __forceinline__ short f2bf(float f) {
    uint32_t u = __builtin_bit_cast(uint32_t, f);
    u += 0x7fffu + ((u >> 16) & 1u);
    return (short)(u >> 16);
}
static __device__ __forceinline__ float bf2f(short h) {
    uint32_t u = ((uint32_t)(unsigned short)h) << 16;
    return __builtin_bit_cast(float, u);
}
static __device__ __forceinline__ void gload16(const void* g, void* l) {
    __builtin_amdgcn_global_load_lds(
        (const __attribute__((address_space(1))) unsigned int*)g,
        (__attribute__((address_space(3))) unsigned int*)l, 16, 0, 0);
}

// ------------------------------------------------------------ prep: fp32 -> bf16
__global__ __launch_bounds__(256)
void cvt_bf16(const float* __restrict__ a, const float* __restrict__ b,
              short* __restrict__ ao, short* __restrict__ bo)
{
    const int id = blockIdx.x * 256 + threadIdx.x;
    const int nA = (M_ * DIM_) / 8;
    const float* src = (id < nA) ? a : b;
    short* dst = (id < nA) ? ao : bo;
    const int c = (id < nA) ? id : id - nA;
    const f32x4 v0 = *(const f32x4*)&src[(size_t)c * 8];
    const f32x4 v1 = *(const f32x4*)&src[(size_t)c * 8 + 4];
    bf16x8 o;
#pragma unroll
    for (int i = 0; i < 4; ++i) { o[i] = f2bf(v0[i]); o[4 + i] = f2bf(v1[i]); }
    *(bf16x8*)&dst[(size_t)c * 8] = o;
}

// ------------------------------------------------------------ prep: W[k][n] -> WT[n][k] bf16
__global__ __launch_bounds__(256)
void wtrans(const float* __restrict__ Wq, const float* __restrict__ Wk,
            const float* __restrict__ Wv, const float* __restrict__ Wo,
            short* __restrict__ WqT, short* __restrict__ WkT,
            short* __restrict__ WvT, short* __restrict__ WoT)
{
    const int z = blockIdx.z;
    const int K = (z == 3) ? 2 * DIM_ : DIM_;
    const int k0 = blockIdx.x * 64;
    if (k0 >= K) return;
    const int n0 = blockIdx.y * 64;
    const float* W = (z == 0) ? Wq : (z == 1) ? Wk : (z == 2) ? Wv : Wo;
    short* WT = (z == 0) ? WqT : (z == 1) ? WkT : (z == 2) ? WvT : WoT;

    __shared__ float ts[64][65];
    const int tid = threadIdx.x;
    {
        const int k = tid >> 2, noff = (tid & 3) * 16;
#pragma unroll
        for (int i = 0; i < 4; ++i)
            *(f32x4*)&ts[k][noff + i * 4] =
                *(const f32x4*)&W[(size_t)(k0 + k) * DIM_ + n0 + noff + i * 4];
    }
    __syncthreads();
    {
        const int n = tid >> 2, koff = (tid & 3) * 16;
#pragma unroll
        for (int c = 0; c < 2; ++c) {
            bf16x8 o;
#pragma unroll
            for (int i = 0; i < 8; ++i) o[i] = f2bf(ts[koff + c * 8 + i][n]);
            *(bf16x8*)&WT[(size_t)(n0 + n) * K + k0 + koff + c * 8] = o;
        }
    }
}

// ------------------------------------------------------------ QKV GEMM (MFMA, gload_lds, BK=64, XOR-swizzled LDS)
__global__ __launch_bounds__(256)
void qkv_mfma(const short* __restrict__ xoutb, const short* __restrict__ xctxb,
              const short* __restrict__ WqT, const short* __restrict__ WkT,
              const short* __restrict__ WvT,
              const float* __restrict__ bq, const float* __restrict__ bk,
              const float* __restrict__ bv,
              short* __restrict__ qh, short* __restrict__ kh, short* __restrict__ vT)
{
    const int z = blockIdx.z;
    const short* A  = (z == 0) ? xoutb : xctxb;
    const short* Bt = (z == 0) ? WqT : (z == 1) ? WkT : WvT;
    const float* bias = (z == 0) ? bq : (z == 1) ? bk : bv;

    const int col0 = blockIdx.x * 128;
    const int row0 = blockIdx.y * 128;
    const int tid = threadIdx.x;
    const int lane = tid & 63;
    const int w = tid >> 6;
    const int wm = (w >> 1) * 64, wn = (w & 1) * 64;
    const int l15 = lane & 15, g = lane >> 4;
    const int sub = lane >> 3, slt = lane & 7;

    __shared__ short As[128 * 64];
    __shared__ short Bs[128 * 64];

    const short* pA[4]; const short* pB[4]; short* ldsA[4]; short* ldsB[4];
#pragma unroll
    for (int i = 0; i < 4; ++i) {
        const int r = w * 32 + i * 8 + sub;
        const int sc = ((slt ^ (r & 7)) * 8);
        pA[i] = A  + (size_t)(row0 + r) * DIM_ + sc;
        pB[i] = Bt + (size_t)(col0 + r) * DIM_ + sc;
        ldsA[i] = &As[(w * 32 + i * 8) * 64];
        ldsB[i] = &Bs[(w * 32 + i * 8) * 64];
    }

    f32x4 acc[4][4];
#pragma unroll
    for (int mi = 0; mi < 4; ++mi)
#pragma unroll
        for (int ni = 0; ni < 4; ++ni) acc[mi][ni] = (f32x4)0.f;

    for (int k0 = 0; k0 < DIM_; k0 += 64) {
#pragma unroll
        for (int i = 0; i < 4; ++i) {
            gload16(pA[i] + k0, ldsA[i]);
            gload16(pB[i] + k0, ldsB[i]);
        }
        __syncthreads();
        bf16x8 af[4][2], bfr[4][2];
#pragma unroll
        for (int mi = 0; mi < 4; ++mi) {
            const int wa = wm + mi * 16 + l15;
#pragma unroll
            for (int ks = 0; ks < 2; ++ks)
                af[mi][ks] = *(const bf16x8*)&As[wa * 64 + (((ks * 4 + g) ^ (wa & 7)) * 8)];
        }
#pragma unroll
        for (int ni = 0; ni < 4; ++ni) {
            const int wb = wn + ni * 16 + l15;
#pragma unroll
            for (int ks = 0; ks < 2; ++ks)
                bfr[ni][ks] = *(const bf16x8*)&Bs[wb * 64 + (((ks * 4 + g) ^ (wb & 7)) * 8)];
        }
#pragma unroll
        for (int mi = 0; mi < 4; ++mi)
#pragma unroll
            for (int ni = 0; ni < 4; ++ni)
#pragma unroll
                for (int ks = 0; ks < 2; ++ks)
                    acc[mi][ni] = __builtin_amdgcn_mfma_f32_16x16x32_bf16(af[mi][ks], bfr[ni][ks], acc[mi][ni], 0, 0, 0);
        __syncthreads();
    }

#pragma unroll
    for (int ni = 0; ni < 4; ++ni) {
        const int col = col0 + wn + ni * 16 + l15;
        const int h = col >> 6, dk = col & 63;
        const float bb = bias[col];
#pragma unroll
        for (int mi = 0; mi < 4; ++mi) {
            const int rowb = row0 + wm + mi * 16 + g * 4;
            const int b = rowb >> 11;
            const int l = rowb & (L_ - 1);
            const int bh = b * 16 + h;
            if (z == 2) {
                bf16x4 o;
#pragma unroll
                for (int r = 0; r < 4; ++r) o[r] = f2bf(acc[mi][ni][r] + bb);
                *(bf16x4*)&vT[(size_t)(bh * 64 + dk) * L_ + l] = o;
            } else {
                short* dst = (z == 0) ? qh : kh;
                const float sc = (z == 0) ? QSCALE : 1.0f;
#pragma unroll
                for (int r = 0; r < 4; ++r)
                    dst[((size_t)bh * L_ + l + r) * DK_ + dk] = f2bf((acc[mi][ni][r] + bb) * sc);
            }
        }
    }
}

// ------------------------------------------------------------ fused attention v4
// 8 waves = 4 q-groups x 2 kv-halves. K dbuf + V staged via gload_lds (XOR swizzle
// both sides). P kept bf16 in LDS. 2-pass online softmax in exp2 domain.
__global__ __launch_bounds__(512, 8)
void attn_mfma(const short* __restrict__ qh, const short* __restrict__ kh,
               const short* __restrict__ vT,
               float* __restrict__ attn, short* __restrict__ ctxTb)
{
    const int bid = blockIdx.x;
    const int wg = (bid & 7) * 128 + (bid >> 3);      // XCD-contiguous
    const int bh = wg >> 5;
    const int q0 = (wg & 31) * 64;

    const int tid = threadIdx.x;
    const int lane = tid & 63;
    const int w = tid >> 6;
    const int wq = w >> 1, wk = w & 1;
    const int l15 = lane & 15, g = lane >> 4;

    __shared__ short Kb0[64 * 64];
    __shared__ short Kb1[64 * 64];
    __shared__ short Vb[64 * 64];
    __shared__ short Psb[64 * 72];                    // bf16 P, 144B row stride
    __shared__ float stat[4][2][16][2];               // [wq][wk][row16][m,s]

    const short* kbase = kh + (size_t)bh * (L_ * DK_);
    const short* vbase = vT + (size_t)bh * (DK_ * L_);

    // gload lane mapping: wave w feeds LDS rows w*8..w*8+7, linear dest, swizzled src
    const int lr = lane >> 3, ls = lane & 7;
    const int srow = w * 8 + lr;
    const short* kSrc = kbase + (size_t)srow * DK_ + ((ls ^ (srow & 7)) * 8);
    const short* vSrc = vbase + (size_t)srow * L_ + ((ls ^ (srow & 7)) * 8);
    short* kDst0 = &Kb0[w * 512];
    short* kDst1 = &Kb1[w * 512];
    short* vDst  = &Vb[w * 512];

    // q fragment (A-operand rows = wq's 16 q rows)
    bf16x8 qf[2];
#pragma unroll
    for (int ks = 0; ks < 2; ++ks)
        qf[ks] = *(const bf16x8*)&qh[((size_t)bh * L_ + q0 + wq * 16 + l15) * DK_ + ks * 32 + g * 8];

    // swizzled LDS read offsets
    int kbOff[2][2], vbOff[4];
#pragma unroll
    for (int cc = 0; cc < 2; ++cc)
#pragma unroll
        for (int ks = 0; ks < 2; ++ks) {
            const int row = wk * 32 + cc * 16 + l15;
            kbOff[cc][ks] = row * 64 + (((ks * 4 + g) ^ (row & 7)) * 8);
        }
#pragma unroll
    for (int nf = 0; nf < 4; ++nf) {
        const int row = nf * 16 + l15;
        vbOff[nf] = row * 64 + (((wk * 4 + g) ^ (row & 7)) * 8);
    }

    // ---------------- pass 1: online stats over this wave's kv-half
    float m[4], s[4];
#pragma unroll
    for (int r = 0; r < 4; ++r) { m[r] = -1e30f; s[r] = 0.f; }

    gload16(kSrc, kDst0);
    __syncthreads();
    for (int t = 0; t < 32; ++t) {
        if (t < 31) gload16(kSrc + (size_t)(t + 1) * 64 * DK_, (t & 1) ? kDst0 : kDst1);
        const short* kb = (t & 1) ? Kb1 : Kb0;
        f32x4 sa[2];
#pragma unroll
        for (int cc = 0; cc < 2; ++cc) sa[cc] = (f32x4)0.f;
#pragma unroll
        for (int cc = 0; cc < 2; ++cc)
#pragma unroll
            for (int ks = 0; ks < 2; ++ks)
                sa[cc] = __builtin_amdgcn_mfma_f32_16x16x32_bf16(qf[ks], *(const bf16x8*)&kb[kbOff[cc][ks]], sa[cc], 0, 0, 0);
#pragma unroll
        for (int r = 0; r < 4; ++r) {
            const float tm = fmaxf(sa[0][r], sa[1][r]);
            const float mn = fmaxf(m[r], tm);
            s[r] = s[r] * exp2f(m[r] - mn) + exp2f(sa[0][r] - mn) + exp2f(sa[1][r] - mn);
            m[r] = mn;
        }
        __syncthreads();
    }
    // combine across the 16 lanes of each col-group
#pragma unroll
    for (int mask = 1; mask <= 8; mask <<= 1) {
#pragma unroll
        for (int r = 0; r < 4; ++r) {
            const float mo = __shfl_xor(m[r], mask);
            const float so = __shfl_xor(s[r], mask);
            const float mn = fmaxf(m[r], mo);
            s[r] = s[r] * exp2f(m[r] - mn) + so * exp2f(mo - mn);
            m[r] = mn;
        }
    }
    if (l15 == 0) {
#pragma unroll
        for (int r = 0; r < 4; ++r) {
            stat[wq][wk][g * 4 + r][0] = m[r];
            stat[wq][wk][g * 4 + r][1] = s[r];
        }
    }
    gload16(kSrc, kDst0);        // K(0) for pass 2
    __syncthreads();
    float inv_s[4];
#pragma unroll
    for (int r = 0; r < 4; ++r) {
        const float m0 = stat[wq][0][g * 4 + r][0], s0 = stat[wq][0][g * 4 + r][1];
        const float m1 = stat[wq][1][g * 4 + r][0], s1 = stat[wq][1][g * 4 + r][1];
        const float mn = fmaxf(m0, m1);
        m[r] = mn;
        inv_s[r] = 1.0f / (s0 * exp2f(m0 - mn) + s1 * exp2f(m1 - mn));
    }

    f32x4 cacc[4];
#pragma unroll
    for (int nf = 0; nf < 4; ++nf) cacc[nf] = (f32x4)0.f;

    float* attnB = attn + ((size_t)bh * L_ + q0) * L_;
    const int arow = tid >> 3, acol = (tid & 7) * 8;

    // ---------------- pass 2: recompute, write attn, PV
    for (int t = 0; t < 32; ++t) {
        if (t < 31) gload16(kSrc + (size_t)(t + 1) * 64 * DK_, (t & 1) ? kDst0 : kDst1);
        gload16(vSrc + t * 64, vDst);
        const short* kb = (t & 1) ? Kb1 : Kb0;
        f32x4 sa[2];
#pragma unroll
        for (int cc = 0; cc < 2; ++cc) sa[cc] = (f32x4)0.f;
#pragma unroll
        for (int cc = 0; cc < 2; ++cc)
#pragma unroll
            for (int ks = 0; ks < 2; ++ks)
                sa[cc] = __builtin_amdgcn_mfma_f32_16x16x32_bf16(qf[ks], *(const bf16x8*)&kb[kbOff[cc][ks]], sa[cc], 0, 0, 0);
#pragma unroll
        for (int cc = 0; cc < 2; ++cc)
#pragma unroll
            for (int r = 0; r < 4; ++r)
                Psb[(wq * 16 + g * 4 + r) * 72 + wk * 32 + cc * 16 + l15] =
                    f2bf(exp2f(sa[cc][r] - m[r]) * inv_s[r]);
        __syncthreads();                              // Ps ready; V(t), K(t+1) landed
        {
            const bf16x8 pv = *(const bf16x8*)&Psb[arow * 72 + acol];
            float* dst = attnB + (size_t)arow * L_ + t * 64 + acol;
            f32x4 o0, o1;
#pragma unroll
            for (int i = 0; i < 4; ++i) { o0[i] = bf2f(pv[i]); o1[i] = bf2f(pv[4 + i]); }
            *(f32x4*)dst = o0;
            *(f32x4*)(dst + 4) = o1;
        }
        const bf16x8 pa = *(const bf16x8*)&Psb[(wq * 16 + l15) * 72 + wk * 32 + g * 8];
#pragma unroll
        for (int nf = 0; nf < 4; ++nf)
            cacc[nf] = __builtin_amdgcn_mfma_f32_16x16x32_bf16(pa, *(const bf16x8*)&Vb[vbOff[nf]], cacc[nf], 0, 0, 0);
        __syncthreads();                              // Ps/Vb consumed
    }

    // epilogue: combine kv-halves, store ctx^T bf16
    float* scr = (float*)&Kb0[0];                     // 16KB scratch (Kb0+Kb1 contiguous? use Kb0/Kb1 halves)
    float* scr1 = (float*)&Kb1[0];
    if (wk) {
#pragma unroll
        for (int nf = 0; nf < 4; ++nf) {
            float* p = (nf < 2) ? scr : scr1;
            *(f32x4*)&p[(((wq * 2) + (nf & 1)) * 64 + lane) * 4] = cacc[nf];
        }
    }
    __syncthreads();
    if (!wk) {
#pragma unroll
        for (int nf = 0; nf < 4; ++nf) {
            const float* p = (nf < 2) ? scr : scr1;
            const f32x4 o = cacc[nf] + *(const f32x4*)&p[(((wq * 2) + (nf & 1)) * 64 + lane) * 4];
            bf16x4 ob;
#pragma unroll
            for (int r = 0; r < 4; ++r) ob[r] = f2bf(o[r]);
            *(bf16x4*)&ctxTb[(size_t)(bh * 64 + nf * 16 + l15) * L_ + q0 + wq * 16 + g * 4] = ob;
        }
    }
}

// ------------------------------------------------------------ output projection (MFMA, gload_lds, gathered A)
__global__ __launch_bounds__(256)
void out_mfma(const short* __restrict__ ctxTb, const short* __restrict__ xoutb,
              const short* __restrict__ WoT, const float* __restrict__ bo,
              float* __restrict__ out)
{
    const int col0 = blockIdx.x * 128;
    const int row0 = blockIdx.y * 128;
    const int tid = threadIdx.x;
    const int lane = tid & 63;
    const int w = tid >> 6;
    const int wm = (w >> 1) * 64, wn = (w & 1) * 64;
    const int l15 = lane & 15, g = lane >> 4;
    const int sub = lane >> 3, slt = lane & 7;

    __shared__ short As[128 * 64];
    __shared__ short Bs[128 * 64];

    const short* pA1[4]; const short* pA2[4]; const short* pB[4];
    short* ldsA[4]; short* ldsB[4];
#pragma unroll
    for (int i = 0; i < 4; ++i) {
        const int r = w * 32 + i * 8 + sub;
        const int rr = row0 + r;
        const int b = rr >> 11, l_ = rr & (L_ - 1);
        const int bh = b * 16 + (l_ >> 7), d = (l_ & 127) >> 1;
        const size_t off1 = ((size_t)(bh * 64 + d) << 11) + (size_t)((l_ & 1) << 10);
        const int sc = ((slt ^ (r & 7)) * 8);
        pA1[i] = ctxTb + off1 + sc;
        pA2[i] = xoutb + (size_t)rr * DIM_ + sc;
        pB[i]  = WoT + (size_t)(col0 + r) * (2 * DIM_) + sc;
        ldsA[i] = &As[(w * 32 + i * 8) * 64];
        ldsB[i] = &Bs[(w * 32 + i * 8) * 64];
    }

    f32x4 acc[4][4];
#pragma unroll
    for (int mi = 0; mi < 4; ++mi)
#pragma unroll
        for (int ni = 0; ni < 4; ++ni) acc[mi][ni] = (f32x4)0.f;

    for (int k0 = 0; k0 < 2 * DIM_; k0 += 64) {
        const bool first = (k0 < DIM_);
        const int kk = first ? k0 : k0 - DIM_;
#pragma unroll
        for (int i = 0; i < 4; ++i) {
            gload16(first ? (pA1[i] + kk) : (pA2[i] + kk), ldsA[i]);
            gload16(pB[i] + k0, ldsB[i]);
        }
        __syncthreads();
        bf16x8 af[4][2], bfr[4][2];
#pragma unroll
        for (int mi = 0; mi < 4; ++mi) {
            const int wa = wm + mi * 16 + l15;
#pragma unroll
            for (int ks = 0; ks < 2; ++ks)
                af[mi][ks] = *(const bf16x8*)&As[wa * 64 + (((ks * 4 + g) ^ (wa & 7)) * 8)];
        }
#pragma unroll
        for (int ni = 0; ni < 4; ++ni) {
            const int wb = wn + ni * 16 + l15;
#pragma unroll
            for (int ks = 0; ks < 2; ++ks)
                bfr[ni][ks] = *(const bf16x8*)&Bs[wb * 64 + (((ks * 4 + g) ^ (wb & 7)) * 8)];
        }
#pragma unroll
        for (int mi = 0; mi < 4; ++mi)
#pragma unroll
            for (int ni = 0; ni < 4; ++ni)
#pragma unroll
                for (int ks = 0; ks < 2; ++ks)
                    acc[mi][ni] = __builtin_amdgcn_mfma_f32_16x16x32_bf16(af[mi][ks], bfr[ni][ks], acc[mi][ni], 0, 0, 0);
        __syncthreads();
    }

#pragma unroll
    for (int ni = 0; ni < 4; ++ni) {
        const int col = col0 + wn + ni * 16 + l15;
        const float bb = bo[col];
#pragma unroll
        for (int mi = 0; mi < 4; ++mi) {
            const int rowb = row0 + wm + mi * 16 + g * 4;
#pragma unroll
            for (int r = 0; r < 4; ++r)
                out[(size_t)(rowb + r) * DIM_ + col] = tanhf(acc[mi][ni][r] + bb);
        }
    }
}

// ------------------------------------------------------------ launch
extern "C" void kernel_launch(void* const* d_in, const int* in_sizes, int n_in,
                              void* d_out, int out_size, void* d_ws, size_t ws_size,
                              hipStream_t stream)
{
    const float* xout = (const float*)d_in[0];
    const float* xctx = (const float*)d_in[1];
    const float* Wq = (const float*)d_in[2];
    const float* bq = (const float*)d_in[3];
    const float* Wk = (const float*)d_in[4];
    const float* bk = (const float*)d_in[5];
    const float* Wv = (const float*)d_in[6];
    const float* bv = (const float*)d_in[7];
    const float* Wo = (const float*)d_in[8];
    const float* bo = (const float*)d_in[9];

    float* out  = (float*)d_out;
    float* attn = out + (size_t)M_ * DIM_;

    short* ws = (short*)d_ws;
    short* xoutb = ws;
    short* xctxb = xoutb + (size_t)M_ * DIM_;
    short* WqT   = xctxb + (size_t)M_ * DIM_;
    short* WkT   = WqT + (size_t)DIM_ * DIM_;
    short* WvT   = WkT + (size_t)DIM_ * DIM_;
    short* WoT   = WvT + (size_t)DIM_ * DIM_;
    short* qh    = WoT + (size_t)2 * DIM_ * DIM_;
    short* kh    = qh + (size_t)BH_ * L_ * DK_;
    short* vT    = kh + (size_t)BH_ * L_ * DK_;
    short* ctxTb = vT + (size_t)BH_ * L_ * DK_;

    cvt_bf16<<<(2 * M_ * DIM_ / 8) / 256, 256, 0, stream>>>(xout, xctx, xoutb, xctxb);
    wtrans<<<dim3(32, 16, 4), 256, 0, stream>>>(Wq, Wk, Wv, Wo, WqT, WkT, WvT, WoT);
    qkv_mfma<<<dim3(DIM_ / 128, M_ / 128, 3), 256, 0, stream>>>(
        xoutb, xctxb, WqT, WkT, WvT, bq, bk, bv, qh, kh, vT);
    attn_mfma<<<1024, 512, 0, stream>>>(qh, kh, vT, attn, ctxTb);
    out_mfma<<<dim3(DIM_ / 128, M_ / 128), 256, 0, stream>>>(ctxTb, xoutb, WoT, bo, out);
}

// Round 5
// 337.985 us; speedup vs baseline: 1.7886x; 1.0536x over previous
//
#include <hip/hip_runtime.h>
#include <math.h>
#include <stdint.h>

#define DIM_ 1024
#define HEADS_ 16
#define DK_ 64
#define B_ 2
#define L_ 2048
#define BH_ (B_*HEADS_)
#define M_ (B_*L_)

typedef __attribute__((ext_vector_type(4))) float f32x4;
typedef __attribute__((ext_vector_type(8))) short bf16x8;
typedef __attribute__((ext_vector_type(4))) short bf16x4;

#define QSCALE 0.18033688f   // 0.125 * log2(e): softmax in exp2 domain

static __device__ __forceinline__ short f2bf(float f) {
    uint32_t u = __builtin_bit_cast(uint32_t, f);
    u += 0x7fffu + ((u >> 16) & 1u);
    return (short)(u >> 16);
}
static __device__ __forceinline__ float bf2f(short h) {
    uint32_t u = ((uint32_t)(unsigned short)h) << 16;
    return __builtin_bit_cast(float, u);
}
static __device__ __forceinline__ void gload16(const void* g, void* l) {
    __builtin_amdgcn_global_load_lds(
        (const __attribute__((address_space(1))) unsigned int*)g,
        (__attribute__((address_space(3))) unsigned int*)l, 16, 0, 0);
}

// ------------------------------------------------------------ prep: fp32 -> bf16
__global__ __launch_bounds__(256)
void cvt_bf16(const float* __restrict__ a, const float* __restrict__ b,
              short* __restrict__ ao, short* __restrict__ bo)
{
    const int id = blockIdx.x * 256 + threadIdx.x;
    const int nA = (M_ * DIM_) / 8;
    const float* src = (id < nA) ? a : b;
    short* dst = (id < nA) ? ao : bo;
    const int c = (id < nA) ? id : id - nA;
    const f32x4 v0 = *(const f32x4*)&src[(size_t)c * 8];
    const f32x4 v1 = *(const f32x4*)&src[(size_t)c * 8 + 4];
    bf16x8 o;
#pragma unroll
    for (int i = 0; i < 4; ++i) { o[i] = f2bf(v0[i]); o[4 + i] = f2bf(v1[i]); }
    *(bf16x8*)&dst[(size_t)c * 8] = o;
}

// ------------------------------------------------------------ prep: W[k][n] -> WT[n][k] bf16
__global__ __launch_bounds__(256)
void wtrans(const float* __restrict__ Wq, const float* __restrict__ Wk,
            const float* __restrict__ Wv, const float* __restrict__ Wo,
            short* __restrict__ WqT, short* __restrict__ WkT,
            short* __restrict__ WvT, short* __restrict__ WoT)
{
    const int z = blockIdx.z;
    const int K = (z == 3) ? 2 * DIM_ : DIM_;
    const int k0 = blockIdx.x * 64;
    if (k0 >= K) return;
    const int n0 = blockIdx.y * 64;
    const float* W = (z == 0) ? Wq : (z == 1) ? Wk : (z == 2) ? Wv : Wo;
    short* WT = (z == 0) ? WqT : (z == 1) ? WkT : (z == 2) ? WvT : WoT;

    __shared__ float ts[64][65];
    const int tid = threadIdx.x;
    {
        const int k = tid >> 2, noff = (tid & 3) * 16;
#pragma unroll
        for (int i = 0; i < 4; ++i)
            *(f32x4*)&ts[k][noff + i * 4] =
                *(const f32x4*)&W[(size_t)(k0 + k) * DIM_ + n0 + noff + i * 4];
    }
    __syncthreads();
    {
        const int n = tid >> 2, koff = (tid & 3) * 16;
#pragma unroll
        for (int c = 0; c < 2; ++c) {
            bf16x8 o;
#pragma unroll
            for (int i = 0; i < 8; ++i) o[i] = f2bf(ts[koff + c * 8 + i][n]);
            *(bf16x8*)&WT[(size_t)(n0 + n) * K + k0 + koff + c * 8] = o;
        }
    }
}

// ------------------------------------------------------------ QKV GEMM (MFMA, gload_lds, BK=64, XOR-swizzled LDS)
__global__ __launch_bounds__(256)
void qkv_mfma(const short* __restrict__ xoutb, const short* __restrict__ xctxb,
              const short* __restrict__ WqT, const short* __restrict__ WkT,
              const short* __restrict__ WvT,
              const float* __restrict__ bq, const float* __restrict__ bk,
              const float* __restrict__ bv,
              short* __restrict__ qh, short* __restrict__ kh, short* __restrict__ vT)
{
    const int z = blockIdx.z;
    const short* A  = (z == 0) ? xoutb : xctxb;
    const short* Bt = (z == 0) ? WqT : (z == 1) ? WkT : WvT;
    const float* bias = (z == 0) ? bq : (z == 1) ? bk : bv;

    // bijective XCD swizzle over the 256 xy-blocks (256 % 8 == 0)
    const int flat = blockIdx.y * 8 + blockIdx.x;
    const int wgs = (flat & 7) * 32 + (flat >> 3);
    const int col0 = (wgs & 7) * 128;
    const int row0 = (wgs >> 3) * 128;
    const int tid = threadIdx.x;
    const int lane = tid & 63;
    const int w = tid >> 6;
    const int wm = (w >> 1) * 64, wn = (w & 1) * 64;
    const int l15 = lane & 15, g = lane >> 4;
    const int sub = lane >> 3, slt = lane & 7;

    __shared__ short As[128 * 64];
    __shared__ short Bs[128 * 64];

    const short* pA[4]; const short* pB[4]; short* ldsA[4]; short* ldsB[4];
#pragma unroll
    for (int i = 0; i < 4; ++i) {
        const int r = w * 32 + i * 8 + sub;
        const int sc = ((slt ^ (r & 7)) * 8);
        pA[i] = A  + (size_t)(row0 + r) * DIM_ + sc;
        pB[i] = Bt + (size_t)(col0 + r) * DIM_ + sc;
        ldsA[i] = &As[(w * 32 + i * 8) * 64];
        ldsB[i] = &Bs[(w * 32 + i * 8) * 64];
    }

    f32x4 acc[4][4];
#pragma unroll
    for (int mi = 0; mi < 4; ++mi)
#pragma unroll
        for (int ni = 0; ni < 4; ++ni) acc[mi][ni] = (f32x4)0.f;

    for (int k0 = 0; k0 < DIM_; k0 += 64) {
#pragma unroll
        for (int i = 0; i < 4; ++i) {
            gload16(pA[i] + k0, ldsA[i]);
            gload16(pB[i] + k0, ldsB[i]);
        }
        __syncthreads();
        bf16x8 af[4][2], bfr[4][2];
#pragma unroll
        for (int mi = 0; mi < 4; ++mi) {
            const int wa = wm + mi * 16 + l15;
#pragma unroll
            for (int ks = 0; ks < 2; ++ks)
                af[mi][ks] = *(const bf16x8*)&As[wa * 64 + (((ks * 4 + g) ^ (wa & 7)) * 8)];
        }
#pragma unroll
        for (int ni = 0; ni < 4; ++ni) {
            const int wb = wn + ni * 16 + l15;
#pragma unroll
            for (int ks = 0; ks < 2; ++ks)
                bfr[ni][ks] = *(const bf16x8*)&Bs[wb * 64 + (((ks * 4 + g) ^ (wb & 7)) * 8)];
        }
        __builtin_amdgcn_s_setprio(1);
#pragma unroll
        for (int mi = 0; mi < 4; ++mi)
#pragma unroll
            for (int ni = 0; ni < 4; ++ni)
#pragma unroll
                for (int ks = 0; ks < 2; ++ks)
                    acc[mi][ni] = __builtin_amdgcn_mfma_f32_16x16x32_bf16(af[mi][ks], bfr[ni][ks], acc[mi][ni], 0, 0, 0);
        __builtin_amdgcn_s_setprio(0);
        __syncthreads();
    }

#pragma unroll
    for (int ni = 0; ni < 4; ++ni) {
        const int col = col0 + wn + ni * 16 + l15;
        const int h = col >> 6, dk = col & 63;
        const float bb = bias[col];
#pragma unroll
        for (int mi = 0; mi < 4; ++mi) {
            const int rowb = row0 + wm + mi * 16 + g * 4;
            const int b = rowb >> 11;
            const int l = rowb & (L_ - 1);
            const int bh = b * 16 + h;
            if (z == 2) {
                bf16x4 o;
#pragma unroll
                for (int r = 0; r < 4; ++r) o[r] = f2bf(acc[mi][ni][r] + bb);
                *(bf16x4*)&vT[(size_t)(bh * 64 + dk) * L_ + l] = o;
            } else {
                short* dst = (z == 0) ? qh : kh;
                const float sc = (z == 0) ? QSCALE : 1.0f;
#pragma unroll
                for (int r = 0; r < 4; ++r)
                    dst[((size_t)bh * L_ + l + r) * DK_ + dk] = f2bf((acc[mi][ni][r] + bb) * sc);
            }
        }
    }
}

// ------------------------------------------------------------ fused attention v4.1
__global__ __launch_bounds__(512, 8)
void attn_mfma(const short* __restrict__ qh, const short* __restrict__ kh,
               const short* __restrict__ vT,
               float* __restrict__ attn, short* __restrict__ ctxTb)
{
    const int bid = blockIdx.x;
    const int wg = (bid & 7) * 128 + (bid >> 3);      // XCD-contiguous
    const int bh = wg >> 5;
    const int q0 = (wg & 31) * 64;

    const int tid = threadIdx.x;
    const int lane = tid & 63;
    const int w = tid >> 6;
    const int wq = w >> 1, wk = w & 1;
    const int l15 = lane & 15, g = lane >> 4;

    __shared__ short Kb0[64 * 64];
    __shared__ short Kb1[64 * 64];
    __shared__ short Vb[64 * 64];
    __shared__ short Psb[64 * 72];                    // bf16 P, 144B row stride
    __shared__ float stat[4][2][16][2];               // [wq][wk][row16][m,s]

    const short* kbase = kh + (size_t)bh * (L_ * DK_);
    const short* vbase = vT + (size_t)bh * (DK_ * L_);

    const int lr = lane >> 3, ls = lane & 7;
    const int srow = w * 8 + lr;
    const short* kSrc = kbase + (size_t)srow * DK_ + ((ls ^ (srow & 7)) * 8);
    const short* vSrc = vbase + (size_t)srow * L_ + ((ls ^ (srow & 7)) * 8);
    short* kDst0 = &Kb0[w * 512];
    short* kDst1 = &Kb1[w * 512];
    short* vDst  = &Vb[w * 512];

    bf16x8 qf[2];
#pragma unroll
    for (int ks = 0; ks < 2; ++ks)
        qf[ks] = *(const bf16x8*)&qh[((size_t)bh * L_ + q0 + wq * 16 + l15) * DK_ + ks * 32 + g * 8];

    int kbOff[2][2], vbOff[4];
#pragma unroll
    for (int cc = 0; cc < 2; ++cc)
#pragma unroll
        for (int ks = 0; ks < 2; ++ks) {
            const int row = wk * 32 + cc * 16 + l15;
            kbOff[cc][ks] = row * 64 + (((ks * 4 + g) ^ (row & 7)) * 8);
        }
#pragma unroll
    for (int nf = 0; nf < 4; ++nf) {
        const int row = nf * 16 + l15;
        vbOff[nf] = row * 64 + (((wk * 4 + g) ^ (row & 7)) * 8);
    }

    // ---------------- pass 1: online stats over this wave's kv-half
    float m[4], s[4];
#pragma unroll
    for (int r = 0; r < 4; ++r) { m[r] = -1e30f; s[r] = 0.f; }

    gload16(kSrc, kDst0);
    __syncthreads();
    for (int t = 0; t < 32; ++t) {
        if (t < 31) gload16(kSrc + (size_t)(t + 1) * 64 * DK_, (t & 1) ? kDst0 : kDst1);
        const short* kb = (t & 1) ? Kb1 : Kb0;
        f32x4 sa[2];
#pragma unroll
        for (int cc = 0; cc < 2; ++cc) sa[cc] = (f32x4)0.f;
        __builtin_amdgcn_s_setprio(1);
#pragma unroll
        for (int cc = 0; cc < 2; ++cc)
#pragma unroll
            for (int ks = 0; ks < 2; ++ks)
                sa[cc] = __builtin_amdgcn_mfma_f32_16x16x32_bf16(qf[ks], *(const bf16x8*)&kb[kbOff[cc][ks]], sa[cc], 0, 0, 0);
        __builtin_amdgcn_s_setprio(0);
#pragma unroll
        for (int r = 0; r < 4; ++r) {
            const float tm = fmaxf(sa[0][r], sa[1][r]);
            const float mn = fmaxf(m[r], tm);
            s[r] = s[r] * exp2f(m[r] - mn) + exp2f(sa[0][r] - mn) + exp2f(sa[1][r] - mn);
            m[r] = mn;
        }
        __syncthreads();
    }
#pragma unroll
    for (int mask = 1; mask <= 8; mask <<= 1) {
#pragma unroll
        for (int r = 0; r < 4; ++r) {
            const float mo = __shfl_xor(m[r], mask);
            const float so = __shfl_xor(s[r], mask);
            const float mn = fmaxf(m[r], mo);
            s[r] = s[r] * exp2f(m[r] - mn) + so * exp2f(mo - mn);
            m[r] = mn;
        }
    }
    if (l15 == 0) {
#pragma unroll
        for (int r = 0; r < 4; ++r) {
            stat[wq][wk][g * 4 + r][0] = m[r];
            stat[wq][wk][g * 4 + r][1] = s[r];
        }
    }
    gload16(kSrc, kDst0);        // K(0) for pass 2
    __syncthreads();
    float inv_s[4];
#pragma unroll
    for (int r = 0; r < 4; ++r) {
        const float m0 = stat[wq][0][g * 4 + r][0], s0 = stat[wq][0][g * 4 + r][1];
        const float m1 = stat[wq][1][g * 4 + r][0], s1 = stat[wq][1][g * 4 + r][1];
        const float mn = fmaxf(m0, m1);
        m[r] = mn;
        inv_s[r] = 1.0f / (s0 * exp2f(m0 - mn) + s1 * exp2f(m1 - mn));
    }

    f32x4 cacc[4];
#pragma unroll
    for (int nf = 0; nf < 4; ++nf) cacc[nf] = (f32x4)0.f;

    float* attnB = attn + ((size_t)bh * L_ + q0) * L_;
    const int arow = tid >> 3, acol = (tid & 7) * 8;

    // ---------------- pass 2: recompute, write attn (nontemporal), PV
    for (int t = 0; t < 32; ++t) {
        if (t < 31) gload16(kSrc + (size_t)(t + 1) * 64 * DK_, (t & 1) ? kDst0 : kDst1);
        gload16(vSrc + t * 64, vDst);
        const short* kb = (t & 1) ? Kb1 : Kb0;
        f32x4 sa[2];
#pragma unroll
        for (int cc = 0; cc < 2; ++cc) sa[cc] = (f32x4)0.f;
        __builtin_amdgcn_s_setprio(1);
#pragma unroll
        for (int cc = 0; cc < 2; ++cc)
#pragma unroll
            for (int ks = 0; ks < 2; ++ks)
                sa[cc] = __builtin_amdgcn_mfma_f32_16x16x32_bf16(qf[ks], *(const bf16x8*)&kb[kbOff[cc][ks]], sa[cc], 0, 0, 0);
        __builtin_amdgcn_s_setprio(0);
#pragma unroll
        for (int cc = 0; cc < 2; ++cc)
#pragma unroll
            for (int r = 0; r < 4; ++r)
                Psb[(wq * 16 + g * 4 + r) * 72 + wk * 32 + cc * 16 + l15] =
                    f2bf(exp2f(sa[cc][r] - m[r]) * inv_s[r]);
        __syncthreads();                              // Ps ready; V(t), K(t+1) landed
        {
            const bf16x8 pv = *(const bf16x8*)&Psb[arow * 72 + acol];
            float* dst = attnB + (size_t)arow * L_ + t * 64 + acol;
            f32x4 o0, o1;
#pragma unroll
            for (int i = 0; i < 4; ++i) { o0[i] = bf2f(pv[i]); o1[i] = bf2f(pv[4 + i]); }
            __builtin_nontemporal_store(o0, (f32x4*)dst);
            __builtin_nontemporal_store(o1, (f32x4*)(dst + 4));
        }
        const bf16x8 pa = *(const bf16x8*)&Psb[(wq * 16 + l15) * 72 + wk * 32 + g * 8];
        __builtin_amdgcn_s_setprio(1);
#pragma unroll
        for (int nf = 0; nf < 4; ++nf)
            cacc[nf] = __builtin_amdgcn_mfma_f32_16x16x32_bf16(pa, *(const bf16x8*)&Vb[vbOff[nf]], cacc[nf], 0, 0, 0);
        __builtin_amdgcn_s_setprio(0);
        __syncthreads();                              // Ps/Vb consumed
    }

    // epilogue: combine kv-halves, store ctx^T bf16
    float* scr = (float*)&Kb0[0];
    float* scr1 = (float*)&Kb1[0];
    if (wk) {
#pragma unroll
        for (int nf = 0; nf < 4; ++nf) {
            float* p = (nf < 2) ? scr : scr1;
            *(f32x4*)&p[(((wq * 2) + (nf & 1)) * 64 + lane) * 4] = cacc[nf];
        }
    }
    __syncthreads();
    if (!wk) {
#pragma unroll
        for (int nf = 0; nf < 4; ++nf) {
            const float* p = (nf < 2) ? scr : scr1;
            const f32x4 o = cacc[nf] + *(const f32x4*)&p[(((wq * 2) + (nf & 1)) * 64 + lane) * 4];
            bf16x4 ob;
#pragma unroll
            for (int r = 0; r < 4; ++r) ob[r] = f2bf(o[r]);
            *(bf16x4*)&ctxTb[(size_t)(bh * 64 + nf * 16 + l15) * L_ + q0 + wq * 16 + g * 4] = ob;
        }
    }
}

// ------------------------------------------------------------ output projection (MFMA, BM=128 BN=64, 2 blocks/CU)
__global__ __launch_bounds__(256)
void out_mfma(const short* __restrict__ ctxTb, const short* __restrict__ xoutb,
              const short* __restrict__ WoT, const float* __restrict__ bo,
              float* __restrict__ out)
{
    // bijective XCD swizzle over 512 blocks (512 % 8 == 0)
    const int flat = blockIdx.y * 16 + blockIdx.x;
    const int wgs = (flat & 7) * 64 + (flat >> 3);
    const int col0 = (wgs & 15) * 64;
    const int row0 = (wgs >> 4) * 128;
    const int tid = threadIdx.x;
    const int lane = tid & 63;
    const int w = tid >> 6;
    const int wm = (w >> 1) * 64, wn = (w & 1) * 32;
    const int l15 = lane & 15, g = lane >> 4;
    const int sub = lane >> 3, slt = lane & 7;

    __shared__ short As[128 * 64];
    __shared__ short Bs[64 * 64];

    const short* pA1[4]; const short* pA2[4]; const short* pB[2];
    short* ldsA[4]; short* ldsB[2];
#pragma unroll
    for (int i = 0; i < 4; ++i) {
        const int r = w * 32 + i * 8 + sub;
        const int rr = row0 + r;
        const int b = rr >> 11, l_ = rr & (L_ - 1);
        const int bh = b * 16 + (l_ >> 7), d = (l_ & 127) >> 1;
        const size_t off1 = ((size_t)(bh * 64 + d) << 11) + (size_t)((l_ & 1) << 10);
        const int sc = ((slt ^ (r & 7)) * 8);
        pA1[i] = ctxTb + off1 + sc;
        pA2[i] = xoutb + (size_t)rr * DIM_ + sc;
        ldsA[i] = &As[(w * 32 + i * 8) * 64];
    }
#pragma unroll
    for (int i = 0; i < 2; ++i) {
        const int r = w * 16 + i * 8 + sub;
        const int sc = ((slt ^ (r & 7)) * 8);
        pB[i]  = WoT + (size_t)(col0 + r) * (2 * DIM_) + sc;
        ldsB[i] = &Bs[(w * 16 + i * 8) * 64];
    }

    f32x4 acc[4][2];
#pragma unroll
    for (int mi = 0; mi < 4; ++mi)
#pragma unroll
        for (int ni = 0; ni < 2; ++ni) acc[mi][ni] = (f32x4)0.f;

    for (int k0 = 0; k0 < 2 * DIM_; k0 += 64) {
        const bool first = (k0 < DIM_);
        const int kk = first ? k0 : k0 - DIM_;
#pragma unroll
        for (int i = 0; i < 4; ++i)
            gload16(first ? (pA1[i] + kk) : (pA2[i] + kk), ldsA[i]);
#pragma unroll
        for (int i = 0; i < 2; ++i)
            gload16(pB[i] + k0, ldsB[i]);
        __syncthreads();
        bf16x8 af[4][2], bfr[2][2];
#pragma unroll
        for (int mi = 0; mi < 4; ++mi) {
            const int wa = wm + mi * 16 + l15;
#pragma unroll
            for (int ks = 0; ks < 2; ++ks)
                af[mi][ks] = *(const bf16x8*)&As[wa * 64 + (((ks * 4 + g) ^ (wa & 7)) * 8)];
        }
#pragma unroll
        for (int ni = 0; ni < 2; ++ni) {
            const int wb = wn + ni * 16 + l15;
#pragma unroll
            for (int ks = 0; ks < 2; ++ks)
                bfr[ni][ks] = *(const bf16x8*)&Bs[wb * 64 + (((ks * 4 + g) ^ (wb & 7)) * 8)];
        }
        __builtin_amdgcn_s_setprio(1);
#pragma unroll
        for (int mi = 0; mi < 4; ++mi)
#pragma unroll
            for (int ni = 0; ni < 2; ++ni)
#pragma unroll
                for (int ks = 0; ks < 2; ++ks)
                    acc[mi][ni] = __builtin_amdgcn_mfma_f32_16x16x32_bf16(af[mi][ks], bfr[ni][ks], acc[mi][ni], 0, 0, 0);
        __builtin_amdgcn_s_setprio(0);
        __syncthreads();
    }

#pragma unroll
    for (int ni = 0; ni < 2; ++ni) {
        const int col = col0 + wn + ni * 16 + l15;
        const float bb = bo[col];
#pragma unroll
        for (int mi = 0; mi < 4; ++mi) {
            const int rowb = row0 + wm + mi * 16 + g * 4;
#pragma unroll
            for (int r = 0; r < 4; ++r)
                out[(size_t)(rowb + r) * DIM_ + col] = tanhf(acc[mi][ni][r] + bb);
        }
    }
}

// ------------------------------------------------------------ launch
extern "C" void kernel_launch(void* const* d_in, const int* in_sizes, int n_in,
                              void* d_out, int out_size, void* d_ws, size_t ws_size,
                              hipStream_t stream)
{
    const float* xout = (const float*)d_in[0];
    const float* xctx = (const float*)d_in[1];
    const float* Wq = (const float*)d_in[2];
    const float* bq = (const float*)d_in[3];
    const float* Wk = (const float*)d_in[4];
    const float* bk = (const float*)d_in[5];
    const float* Wv = (const float*)d_in[6];
    const float* bv = (const float*)d_in[7];
    const float* Wo = (const float*)d_in[8];
    const float* bo = (const float*)d_in[9];

    float* out  = (float*)d_out;
    float* attn = out + (size_t)M_ * DIM_;

    short* ws = (short*)d_ws;
    short* xoutb = ws;
    short* xctxb = xoutb + (size_t)M_ * DIM_;
    short* WqT   = xctxb + (size_t)M_ * DIM_;
    short* WkT   = WqT + (size_t)DIM_ * DIM_;
    short* WvT   = WkT + (size_t)DIM_ * DIM_;
    short* WoT   = WvT + (size_t)DIM_ * DIM_;
    short* qh    = WoT + (size_t)2 * DIM_ * DIM_;
    short* kh    = qh + (size_t)BH_ * L_ * DK_;
    short* vT    = kh + (size_t)BH_ * L_ * DK_;
    short* ctxTb = vT + (size_t)BH_ * L_ * DK_;

    cvt_bf16<<<(2 * M_ * DIM_ / 8) / 256, 256, 0, stream>>>(xout, xctx, xoutb, xctxb);
    wtrans<<<dim3(32, 16, 4), 256, 0, stream>>>(Wq, Wk, Wv, Wo, WqT, WkT, WvT, WoT);
    qkv_mfma<<<dim3(8, 32, 3), 256, 0, stream>>>(
        xoutb, xctxb, WqT, WkT, WvT, bq, bk, bv, qh, kh, vT);
    attn_mfma<<<1024, 512, 0, stream>>>(qh, kh, vT, attn, ctxTb);
    out_mfma<<<dim3(16, 32), 256, 0, stream>>>(ctxTb, xoutb, WoT, bo, out);
}

// Round 6
// 283.689 us; speedup vs baseline: 2.1309x; 1.1914x over previous
//
#include <hip/hip_runtime.h>
#include <math.h>
#include <stdint.h>

#define DIM_ 1024
#define HEADS_ 16
#define DK_ 64
#define B_ 2
#define L_ 2048
#define BH_ (B_*HEADS_)
#define M_ (B_*L_)

typedef __attribute__((ext_vector_type(4))) float f32x4;
typedef __attribute__((ext_vector_type(8))) short bf16x8;
typedef __attribute__((ext_vector_type(4))) short bf16x4;

#define QSCALE 0.18033688f   // 0.125 * log2(e): softmax in exp2 domain

static __device__ __forceinline__ short f2bf(float f) {
    uint32_t u = __builtin_bit_cast(uint32_t, f);
    u += 0x7fffu + ((u >> 16) & 1u);
    return (short)(u >> 16);
}
static __device__ __forceinline__ float bf2f(short h) {
    uint32_t u = ((uint32_t)(unsigned short)h) << 16;
    return __builtin_bit_cast(float, u);
}
static __device__ __forceinline__ void gload16(const void* g, void* l) {
    __builtin_amdgcn_global_load_lds(
        (const __attribute__((address_space(1))) unsigned int*)g,
        (__attribute__((address_space(3))) unsigned int*)l, 16, 0, 0);
}

// ------------------------------------------------------------ prep: fp32 -> bf16
__global__ __launch_bounds__(256)
void cvt_bf16(const float* __restrict__ a, const float* __restrict__ b,
              short* __restrict__ ao, short* __restrict__ bo)
{
    const int id = blockIdx.x * 256 + threadIdx.x;
    const int nA = (M_ * DIM_) / 8;
    const float* src = (id < nA) ? a : b;
    short* dst = (id < nA) ? ao : bo;
    const int c = (id < nA) ? id : id - nA;
    const f32x4 v0 = *(const f32x4*)&src[(size_t)c * 8];
    const f32x4 v1 = *(const f32x4*)&src[(size_t)c * 8 + 4];
    bf16x8 o;
#pragma unroll
    for (int i = 0; i < 4; ++i) { o[i] = f2bf(v0[i]); o[4 + i] = f2bf(v1[i]); }
    *(bf16x8*)&dst[(size_t)c * 8] = o;
}

// ------------------------------------------------------------ prep: W[k][n] -> WT[n][k] bf16
__global__ __launch_bounds__(256)
void wtrans(const float* __restrict__ Wq, const float* __restrict__ Wk,
            const float* __restrict__ Wv, const float* __restrict__ Wo,
            short* __restrict__ WqT, short* __restrict__ WkT,
            short* __restrict__ WvT, short* __restrict__ WoT)
{
    const int z = blockIdx.z;
    const int K = (z == 3) ? 2 * DIM_ : DIM_;
    const int k0 = blockIdx.x * 64;
    if (k0 >= K) return;
    const int n0 = blockIdx.y * 64;
    const float* W = (z == 0) ? Wq : (z == 1) ? Wk : (z == 2) ? Wv : Wo;
    short* WT = (z == 0) ? WqT : (z == 1) ? WkT : (z == 2) ? WvT : WoT;

    __shared__ float ts[64][65];
    const int tid = threadIdx.x;
    {
        const int k = tid >> 2, noff = (tid & 3) * 16;
#pragma unroll
        for (int i = 0; i < 4; ++i)
            *(f32x4*)&ts[k][noff + i * 4] =
                *(const f32x4*)&W[(size_t)(k0 + k) * DIM_ + n0 + noff + i * 4];
    }
    __syncthreads();
    {
        const int n = tid >> 2, koff = (tid & 3) * 16;
#pragma unroll
        for (int c = 0; c < 2; ++c) {
            bf16x8 o;
#pragma unroll
            for (int i = 0; i < 8; ++i) o[i] = f2bf(ts[koff + c * 8 + i][n]);
            *(bf16x8*)&WT[(size_t)(n0 + n) * K + k0 + koff + c * 8] = o;
        }
    }
}

// ------------------------------------------------------------ QKV GEMM (MFMA, gload_lds, BK=64, XOR-swizzled LDS)
__global__ __launch_bounds__(256)
void qkv_mfma(const short* __restrict__ xoutb, const short* __restrict__ xctxb,
              const short* __restrict__ WqT, const short* __restrict__ WkT,
              const short* __restrict__ WvT,
              const float* __restrict__ bq, const float* __restrict__ bk,
              const float* __restrict__ bv,
              short* __restrict__ qh, short* __restrict__ kh, short* __restrict__ vT)
{
    const int z = blockIdx.z;
    const short* A  = (z == 0) ? xoutb : xctxb;
    const short* Bt = (z == 0) ? WqT : (z == 1) ? WkT : WvT;
    const float* bias = (z == 0) ? bq : (z == 1) ? bk : bv;

    const int flat = blockIdx.y * 8 + blockIdx.x;
    const int wgs = (flat & 7) * 32 + (flat >> 3);
    const int col0 = (wgs & 7) * 128;
    const int row0 = (wgs >> 3) * 128;
    const int tid = threadIdx.x;
    const int lane = tid & 63;
    const int w = tid >> 6;
    const int wm = (w >> 1) * 64, wn = (w & 1) * 64;
    const int l15 = lane & 15, g = lane >> 4;
    const int sub = lane >> 3, slt = lane & 7;

    __shared__ short As[128 * 64];
    __shared__ short Bs[128 * 64];

    const short* pA[4]; const short* pB[4]; short* ldsA[4]; short* ldsB[4];
#pragma unroll
    for (int i = 0; i < 4; ++i) {
        const int r = w * 32 + i * 8 + sub;
        const int sc = ((slt ^ (r & 7)) * 8);
        pA[i] = A  + (size_t)(row0 + r) * DIM_ + sc;
        pB[i] = Bt + (size_t)(col0 + r) * DIM_ + sc;
        ldsA[i] = &As[(w * 32 + i * 8) * 64];
        ldsB[i] = &Bs[(w * 32 + i * 8) * 64];
    }

    f32x4 acc[4][4];
#pragma unroll
    for (int mi = 0; mi < 4; ++mi)
#pragma unroll
        for (int ni = 0; ni < 4; ++ni) acc[mi][ni] = (f32x4)0.f;

    for (int k0 = 0; k0 < DIM_; k0 += 64) {
#pragma unroll
        for (int i = 0; i < 4; ++i) {
            gload16(pA[i] + k0, ldsA[i]);
            gload16(pB[i] + k0, ldsB[i]);
        }
        __syncthreads();
        bf16x8 af[4][2], bfr[4][2];
#pragma unroll
        for (int mi = 0; mi < 4; ++mi) {
            const int wa = wm + mi * 16 + l15;
#pragma unroll
            for (int ks = 0; ks < 2; ++ks)
                af[mi][ks] = *(const bf16x8*)&As[wa * 64 + (((ks * 4 + g) ^ (wa & 7)) * 8)];
        }
#pragma unroll
        for (int ni = 0; ni < 4; ++ni) {
            const int wb = wn + ni * 16 + l15;
#pragma unroll
            for (int ks = 0; ks < 2; ++ks)
                bfr[ni][ks] = *(const bf16x8*)&Bs[wb * 64 + (((ks * 4 + g) ^ (wb & 7)) * 8)];
        }
        __builtin_amdgcn_s_setprio(1);
#pragma unroll
        for (int mi = 0; mi < 4; ++mi)
#pragma unroll
            for (int ni = 0; ni < 4; ++ni)
#pragma unroll
                for (int ks = 0; ks < 2; ++ks)
                    acc[mi][ni] = __builtin_amdgcn_mfma_f32_16x16x32_bf16(af[mi][ks], bfr[ni][ks], acc[mi][ni], 0, 0, 0);
        __builtin_amdgcn_s_setprio(0);
        __syncthreads();
    }

#pragma unroll
    for (int ni = 0; ni < 4; ++ni) {
        const int col = col0 + wn + ni * 16 + l15;
        const int h = col >> 6, dk = col & 63;
        const float bb = bias[col];
#pragma unroll
        for (int mi = 0; mi < 4; ++mi) {
            const int rowb = row0 + wm + mi * 16 + g * 4;
            const int b = rowb >> 11;
            const int l = rowb & (L_ - 1);
            const int bh = b * 16 + h;
            if (z == 2) {
                bf16x4 o;
#pragma unroll
                for (int r = 0; r < 4; ++r) o[r] = f2bf(acc[mi][ni][r] + bb);
                *(bf16x4*)&vT[(size_t)(bh * 64 + dk) * L_ + l] = o;
            } else {
                short* dst = (z == 0) ? qh : kh;
                const float sc = (z == 0) ? QSCALE : 1.0f;
#pragma unroll
                for (int r = 0; r < 4; ++r)
                    dst[((size_t)bh * L_ + l + r) * DK_ + dk] = f2bf((acc[mi][ni][r] + bb) * sc);
            }
        }
    }
}

// ------------------------------------------------------------ fused attention v5
// Raw s_barrier + counted vmcnt (T3/T4): attn stores and next-tile gloads stay in
// flight across barriers. attn written fp32 direct from registers.
__global__ __launch_bounds__(512, 8)
void attn_mfma(const short* __restrict__ qh, const short* __restrict__ kh,
               const short* __restrict__ vT,
               float* __restrict__ attn, short* __restrict__ ctxTb)
{
    const int bid = blockIdx.x;
    const int wg = (bid & 7) * 128 + (bid >> 3);      // XCD-contiguous
    const int bh = wg >> 5;
    const int q0 = (wg & 31) * 64;

    const int tid = threadIdx.x;
    const int lane = tid & 63;
    const int w = tid >> 6;
    const int wq = w >> 1, wk = w & 1;
    const int l15 = lane & 15, g = lane >> 4;

    __shared__ short Kb0[64 * 64];
    __shared__ short Kb1[64 * 64];
    __shared__ short Vb[64 * 64];
    __shared__ short Psb[64 * 72];
    __shared__ float stat[4][2][16][2];

    const short* kbase = kh + (size_t)bh * (L_ * DK_);
    const short* vbase = vT + (size_t)bh * (DK_ * L_);

    const int lr = lane >> 3, ls = lane & 7;
    const int srow = w * 8 + lr;
    const short* kSrc = kbase + (size_t)srow * DK_ + ((ls ^ (srow & 7)) * 8);
    const short* vSrc = vbase + (size_t)srow * L_ + ((ls ^ (srow & 7)) * 8);
    short* kDst0 = &Kb0[w * 512];
    short* kDst1 = &Kb1[w * 512];
    short* vDst  = &Vb[w * 512];

    bf16x8 qf[2];
#pragma unroll
    for (int ks = 0; ks < 2; ++ks)
        qf[ks] = *(const bf16x8*)&qh[((size_t)bh * L_ + q0 + wq * 16 + l15) * DK_ + ks * 32 + g * 8];

    int kbOff[2][2], vbOff[4];
#pragma unroll
    for (int cc = 0; cc < 2; ++cc)
#pragma unroll
        for (int ks = 0; ks < 2; ++ks) {
            const int row = wk * 32 + cc * 16 + l15;
            kbOff[cc][ks] = row * 64 + (((ks * 4 + g) ^ (row & 7)) * 8);
        }
#pragma unroll
    for (int nf = 0; nf < 4; ++nf) {
        const int row = nf * 16 + l15;
        vbOff[nf] = row * 64 + (((wk * 4 + g) ^ (row & 7)) * 8);
    }

    // ---------------- pass 1: online stats (raw barriers, counted waits)
    float m[4], s[4];
#pragma unroll
    for (int r = 0; r < 4; ++r) { m[r] = -1e30f; s[r] = 0.f; }

    gload16(kSrc, kDst0);
    asm volatile("s_waitcnt vmcnt(0)" ::: "memory");
    __builtin_amdgcn_sched_barrier(0);
    __builtin_amdgcn_s_barrier();
    for (int t = 0; t < 32; ++t) {
        if (t) {
            asm volatile("s_waitcnt vmcnt(0)" ::: "memory");  // K(t) landed (issued a full iter ago)
            __builtin_amdgcn_sched_barrier(0);
            __builtin_amdgcn_s_barrier();
        }
        if (t < 31) gload16(kSrc + (size_t)(t + 1) * 64 * DK_, (t & 1) ? kDst0 : kDst1);
        const short* kb = (t & 1) ? Kb1 : Kb0;
        f32x4 sa[2];
#pragma unroll
        for (int cc = 0; cc < 2; ++cc) sa[cc] = (f32x4)0.f;
        __builtin_amdgcn_s_setprio(1);
#pragma unroll
        for (int cc = 0; cc < 2; ++cc)
#pragma unroll
            for (int ks = 0; ks < 2; ++ks)
                sa[cc] = __builtin_amdgcn_mfma_f32_16x16x32_bf16(qf[ks], *(const bf16x8*)&kb[kbOff[cc][ks]], sa[cc], 0, 0, 0);
        __builtin_amdgcn_s_setprio(0);
#pragma unroll
        for (int r = 0; r < 4; ++r) {
            const float tm = fmaxf(sa[0][r], sa[1][r]);
            const float mn = fmaxf(m[r], tm);
            s[r] = s[r] * exp2f(m[r] - mn) + exp2f(sa[0][r] - mn) + exp2f(sa[1][r] - mn);
            m[r] = mn;
        }
    }
#pragma unroll
    for (int mask = 1; mask <= 8; mask <<= 1) {
#pragma unroll
        for (int r = 0; r < 4; ++r) {
            const float mo = __shfl_xor(m[r], mask);
            const float so = __shfl_xor(s[r], mask);
            const float mn = fmaxf(m[r], mo);
            s[r] = s[r] * exp2f(m[r] - mn) + so * exp2f(mo - mn);
            m[r] = mn;
        }
    }
    if (l15 == 0) {
#pragma unroll
        for (int r = 0; r < 4; ++r) {
            stat[wq][wk][g * 4 + r][0] = m[r];
            stat[wq][wk][g * 4 + r][1] = s[r];
        }
    }
    gload16(kSrc, kDst0);                             // K(0) for pass 2
    asm volatile("s_waitcnt lgkmcnt(0)" ::: "memory"); // stat visible
    __builtin_amdgcn_s_barrier();
    float inv_s[4];
#pragma unroll
    for (int r = 0; r < 4; ++r) {
        const float m0 = stat[wq][0][g * 4 + r][0], s0 = stat[wq][0][g * 4 + r][1];
        const float m1 = stat[wq][1][g * 4 + r][0], s1 = stat[wq][1][g * 4 + r][1];
        const float mn = fmaxf(m0, m1);
        m[r] = mn;
        inv_s[r] = 1.0f / (s0 * exp2f(m0 - mn) + s1 * exp2f(m1 - mn));
    }

    f32x4 cacc[4];
#pragma unroll
    for (int nf = 0; nf < 4; ++nf) cacc[nf] = (f32x4)0.f;

    float* attnB = attn + ((size_t)bh * L_ + q0) * L_;

    asm volatile("s_waitcnt vmcnt(0)" ::: "memory");   // K(0) landed
    __builtin_amdgcn_sched_barrier(0);
    __builtin_amdgcn_s_barrier();

    // ---------------- pass 2: recompute, fp32 register attn stores, PV
    // per-iter vmem issue order: V(t), K(t+1), stores(t)x8
    for (int t = 0; t < 32; ++t) {
        if (t) {
            asm volatile("s_waitcnt vmcnt(8)" ::: "memory");   // K(t) landed; stores keep flying
            __builtin_amdgcn_sched_barrier(0);
            __builtin_amdgcn_s_barrier();
        }
        gload16(vSrc + t * 64, vDst);                           // V(t)
        {
            const int tn = (t < 31) ? t + 1 : t;                // harmless reload at t=31
            gload16(kSrc + (size_t)tn * 64 * DK_, (t & 1) ? kDst0 : kDst1);
        }
        const short* kb = (t & 1) ? Kb1 : Kb0;
        f32x4 sa[2];
#pragma unroll
        for (int cc = 0; cc < 2; ++cc) sa[cc] = (f32x4)0.f;
        __builtin_amdgcn_s_setprio(1);
#pragma unroll
        for (int cc = 0; cc < 2; ++cc)
#pragma unroll
            for (int ks = 0; ks < 2; ++ks)
                sa[cc] = __builtin_amdgcn_mfma_f32_16x16x32_bf16(qf[ks], *(const bf16x8*)&kb[kbOff[cc][ks]], sa[cc], 0, 0, 0);
        __builtin_amdgcn_s_setprio(0);
#pragma unroll
        for (int cc = 0; cc < 2; ++cc)
#pragma unroll
            for (int r = 0; r < 4; ++r) {
                const float p = exp2f(sa[cc][r] - m[r]) * inv_s[r];
                Psb[(wq * 16 + g * 4 + r) * 72 + wk * 32 + cc * 16 + l15] = f2bf(p);
                __builtin_nontemporal_store(
                    p, attnB + (size_t)(wq * 16 + g * 4 + r) * L_ + t * 64 + wk * 32 + cc * 16 + l15);
            }
        // V(t) landed (9 newer: K(t+1)+8 stores), Psb visible
        asm volatile("s_waitcnt vmcnt(9) lgkmcnt(0)" ::: "memory");
        __builtin_amdgcn_sched_barrier(0);
        __builtin_amdgcn_s_barrier();
        const bf16x8 pa = *(const bf16x8*)&Psb[(wq * 16 + l15) * 72 + wk * 32 + g * 8];
        __builtin_amdgcn_s_setprio(1);
#pragma unroll
        for (int nf = 0; nf < 4; ++nf)
            cacc[nf] = __builtin_amdgcn_mfma_f32_16x16x32_bf16(pa, *(const bf16x8*)&Vb[vbOff[nf]], cacc[nf], 0, 0, 0);
        __builtin_amdgcn_s_setprio(0);
    }

    // epilogue: combine kv-halves, store ctx^T bf16
    __syncthreads();
    float* scr = (float*)&Kb0[0];
    float* scr1 = (float*)&Kb1[0];
    if (wk) {
#pragma unroll
        for (int nf = 0; nf < 4; ++nf) {
            float* p = (nf < 2) ? scr : scr1;
            *(f32x4*)&p[(((wq * 2) + (nf & 1)) * 64 + lane) * 4] = cacc[nf];
        }
    }
    __syncthreads();
    if (!wk) {
#pragma unroll
        for (int nf = 0; nf < 4; ++nf) {
            const float* p = (nf < 2) ? scr : scr1;
            const f32x4 o = cacc[nf] + *(const f32x4*)&p[(((wq * 2) + (nf & 1)) * 64 + lane) * 4];
            bf16x4 ob;
#pragma unroll
            for (int r = 0; r < 4; ++r) ob[r] = f2bf(o[r]);
            *(bf16x4*)&ctxTb[(size_t)(bh * 64 + nf * 16 + l15) * L_ + q0 + wq * 16 + g * 4] = ob;
        }
    }
}

// ------------------------------------------------------------ output projection (MFMA, BM=128 BN=64, 2 blocks/CU)
__global__ __launch_bounds__(256)
void out_mfma(const short* __restrict__ ctxTb, const short* __restrict__ xoutb,
              const short* __restrict__ WoT, const float* __restrict__ bo,
              float* __restrict__ out)
{
    const int flat = blockIdx.y * 16 + blockIdx.x;
    const int wgs = (flat & 7) * 64 + (flat >> 3);
    const int col0 = (wgs & 15) * 64;
    const int row0 = (wgs >> 4) * 128;
    const int tid = threadIdx.x;
    const int lane = tid & 63;
    const int w = tid >> 6;
    const int wm = (w >> 1) * 64, wn = (w & 1) * 32;
    const int l15 = lane & 15, g = lane >> 4;
    const int sub = lane >> 3, slt = lane & 7;

    __shared__ short As[128 * 64];
    __shared__ short Bs[64 * 64];

    const short* pA1[4]; const short* pA2[4]; const short* pB[2];
    short* ldsA[4]; short* ldsB[2];
#pragma unroll
    for (int i = 0; i < 4; ++i) {
        const int r = w * 32 + i * 8 + sub;
        const int rr = row0 + r;
        const int b = rr >> 11, l_ = rr & (L_ - 1);
        const int bh = b * 16 + (l_ >> 7), d = (l_ & 127) >> 1;
        const size_t off1 = ((size_t)(bh * 64 + d) << 11) + (size_t)((l_ & 1) << 10);
        const int sc = ((slt ^ (r & 7)) * 8);
        pA1[i] = ctxTb + off1 + sc;
        pA2[i] = xoutb + (size_t)rr * DIM_ + sc;
        ldsA[i] = &As[(w * 32 + i * 8) * 64];
    }
#pragma unroll
    for (int i = 0; i < 2; ++i) {
        const int r = w * 16 + i * 8 + sub;
        const int sc = ((slt ^ (r & 7)) * 8);
        pB[i]  = WoT + (size_t)(col0 + r) * (2 * DIM_) + sc;
        ldsB[i] = &Bs[(w * 16 + i * 8) * 64];
    }

    f32x4 acc[4][2];
#pragma unroll
    for (int mi = 0; mi < 4; ++mi)
#pragma unroll
        for (int ni = 0; ni < 2; ++ni) acc[mi][ni] = (f32x4)0.f;

    for (int k0 = 0; k0 < 2 * DIM_; k0 += 64) {
        const bool first = (k0 < DIM_);
        const int kk = first ? k0 : k0 - DIM_;
#pragma unroll
        for (int i = 0; i < 4; ++i)
            gload16(first ? (pA1[i] + kk) : (pA2[i] + kk), ldsA[i]);
#pragma unroll
        for (int i = 0; i < 2; ++i)
            gload16(pB[i] + k0, ldsB[i]);
        __syncthreads();
        bf16x8 af[4][2], bfr[2][2];
#pragma unroll
        for (int mi = 0; mi < 4; ++mi) {
            const int wa = wm + mi * 16 + l15;
#pragma unroll
            for (int ks = 0; ks < 2; ++ks)
                af[mi][ks] = *(const bf16x8*)&As[wa * 64 + (((ks * 4 + g) ^ (wa & 7)) * 8)];
        }
#pragma unroll
        for (int ni = 0; ni < 2; ++ni) {
            const int wb = wn + ni * 16 + l15;
#pragma unroll
            for (int ks = 0; ks < 2; ++ks)
                bfr[ni][ks] = *(const bf16x8*)&Bs[wb * 64 + (((ks * 4 + g) ^ (wb & 7)) * 8)];
        }
        __builtin_amdgcn_s_setprio(1);
#pragma unroll
        for (int mi = 0; mi < 4; ++mi)
#pragma unroll
            for (int ni = 0; ni < 2; ++ni)
#pragma unroll
                for (int ks = 0; ks < 2; ++ks)
                    acc[mi][ni] = __builtin_amdgcn_mfma_f32_16x16x32_bf16(af[mi][ks], bfr[ni][ks], acc[mi][ni], 0, 0, 0);
        __builtin_amdgcn_s_setprio(0);
        __syncthreads();
    }

#pragma unroll
    for (int ni = 0; ni < 2; ++ni) {
        const int col = col0 + wn + ni * 16 + l15;
        const float bb = bo[col];
#pragma unroll
        for (int mi = 0; mi < 4; ++mi) {
            const int rowb = row0 + wm + mi * 16 + g * 4;
#pragma unroll
            for (int r = 0; r < 4; ++r)
                out[(size_t)(rowb + r) * DIM_ + col] = tanhf(acc[mi][ni][r] + bb);
        }
    }
}

// ------------------------------------------------------------ launch
extern "C" void kernel_launch(void* const* d_in, const int* in_sizes, int n_in,
                              void* d_out, int out_size, void* d_ws, size_t ws_size,
                              hipStream_t stream)
{
    const float* xout = (const float*)d_in[0];
    const float* xctx = (const float*)d_in[1];
    const float* Wq = (const float*)d_in[2];
    const float* bq = (const float*)d_in[3];
    const float* Wk = (const float*)d_in[4];
    const float* bk = (const float*)d_in[5];
    const float* Wv = (const float*)d_in[6];
    const float* bv = (const float*)d_in[7];
    const float* Wo = (const float*)d_in[8];
    const float* bo = (const float*)d_in[9];

    float* out  = (float*)d_out;
    float* attn = out + (size_t)M_ * DIM_;

    short* ws = (short*)d_ws;
    short* xoutb = ws;
    short* xctxb = xoutb + (size_t)M_ * DIM_;
    short* WqT   = xctxb + (size_t)M_ * DIM_;
    short* WkT   = WqT + (size_t)DIM_ * DIM_;
    short* WvT   = WkT + (size_t)DIM_ * DIM_;
    short* WoT   = WvT + (size_t)DIM_ * DIM_;
    short* qh    = WoT + (size_t)2 * DIM_ * DIM_;
    short* kh    = qh + (size_t)BH_ * L_ * DK_;
    short* vT    = kh + (size_t)BH_ * L_ * DK_;
    short* ctxTb = vT + (size_t)BH_ * L_ * DK_;

    cvt_bf16<<<(2 * M_ * DIM_ / 8) / 256, 256, 0, stream>>>(xout, xctx, xoutb, xctxb);
    wtrans<<<dim3(32, 16, 4), 256, 0, stream>>>(Wq, Wk, Wv, Wo, WqT, WkT, WvT, WoT);
    qkv_mfma<<<dim3(8, 32, 3), 256, 0, stream>>>(
        xoutb, xctxb, WqT, WkT, WvT, bq, bk, bv, qh, kh, vT);
    attn_mfma<<<1024, 512, 0, stream>>>(qh, kh, vT, attn, ctxTb);
    out_mfma<<<dim3(16, 32), 256, 0, stream>>>(ctxTb, xoutb, WoT, bo, out);
}